// Round 12
// baseline (376.583 us; speedup 1.0000x reference)
//
#include <hip/hip_runtime.h>
#include <hip/hip_bf16.h>

#define BB 4
#define NN 2048
#define NROWS (BB*NN)   // 8192

typedef unsigned short u16;
typedef __bf16 bf16x8 __attribute__((ext_vector_type(8)));
typedef u16    u16x8  __attribute__((ext_vector_type(8)));
typedef u16    u16x4  __attribute__((ext_vector_type(4)));
typedef float  fx4    __attribute__((ext_vector_type(4)));

__device__ __forceinline__ float bf2f(u16 u){
  union { float f; unsigned int i; } x; x.i = ((unsigned int)u) << 16; return x.f;
}
__device__ __forceinline__ u16 f2bf(float f){
  union { float f; unsigned int i; } x; x.f = f;
  unsigned int i = x.i;
  i += 0x7fffu + ((i >> 16) & 1u);
  return (u16)(i >> 16);
}
__device__ __forceinline__ float geluf(float x){
  return 0.5f * x * (1.0f + erff(x * 0.70710678118654752f));
}
__device__ __forceinline__ void gload16(const void* g, void* l){
  __builtin_amdgcn_global_load_lds((const __attribute__((address_space(1))) unsigned int*)g,
                                   (__attribute__((address_space(3))) unsigned int*)l, 16, 0, 0);
}

// flags[0]=1 if float inputs fp32 (else bf16); flags[1]=1 if mask byte-packed
__global__ __launch_bounds__(256) void sniff_k(const u16* tokens, const unsigned int* mask, int* flags){
  __shared__ int s_f32, s_byte;
  if (threadIdx.x == 0) { s_f32 = 0; s_byte = 0; }
  __syncthreads();
  for (int i = threadIdx.x; i < 4096; i += 256) {
    float v = bf2f(tokens[i]);
    if (!(fabsf(v) < 1e10f)) atomicOr(&s_f32, 1);
  }
  for (int i = threadIdx.x; i < 2048; i += 256) {
    if (mask[i] > 1u) atomicOr(&s_byte, 1);
  }
  __syncthreads();
  if (threadIdx.x == 0) { flags[0] = s_f32; flags[1] = s_byte; }
}

// merged: blocks [0,4096): rope + m32 + params + zero(ctx,kS) + tokbf(f32-only, x4) grid-stride;
// blocks [4096,5120): conv weights w[o][c][kk] -> W2[kk][o][c];
// blocks [5120,5696): LDS tile transpose [K][N]->[N][K] for the three dense weights
__global__ __launch_bounds__(256) void misc2_k(const void* mask, const void* tokens,
                                               const void* p0, const void* p1, const void* p2,
                                               const void* p3, const void* p4, const void* p5,
                                               const void* p6, const void* p7,
                                               const int* flags, float* rope, int* m32,
                                               float* params, float* ctx, float* kS, u16* tokbf,
                                               const void* w_qkv, const void* w_out, const void* ff_w,
                                               const void* w_narrow, const void* w_wide,
                                               u16* wqkvt, u16* woutt, u16* ffwt,
                                               u16* wtN2, u16* wtW2){
  int bid = blockIdx.x;
  int tid = threadIdx.x;
  int f = flags[0];
  if (bid < 4096) {
    const void* srcs[8] = {p0,p1,p2,p3,p4,p5,p6,p7};
    int mbyte = flags[1];
    const int T = 276480 + 1048576;   // ...+ tokbf handled x4 (f32 path only)
    for (int i = bid*256 + tid; i < T; i += 4096*256) {
      if (i < 131072) {
        int p = i >> 6, j = i & 63;
        int jj = (j < 32) ? j : j - 32;
        float invf = exp2f(-(float)jj * (13.287712379549449f/32.0f));  // 10000^(-jj/32)
        float prod = (float)p * invf;
        rope[i] = (j < 32) ? sinf(prod) : cosf(prod);
      } else if (i < 139264) {
        int k = i - 131072;
        int v = mbyte ? (int)((const unsigned char*)mask)[k] : ((const int*)mask)[k];
        m32[k] = v ? 1 : 0;
      } else if (i < 143360) {
        int k = i - 139264;
        int pid = k >> 9, j = k & 511;
        const void* s = srcs[pid];
        params[k] = f ? ((const float*)s)[j] : bf2f(((const u16*)s)[j]);
      } else if (i < 274432) {
        ctx[i - 143360] = 0.0f;
      } else if (i < 276480) {
        kS[i - 274432] = 0.0f;
      } else if (f) {
        // fp32 input: convert tokens -> bf16 tokbf, 4 elems per item
        int k4 = (i - 276480) * 4;
        float4 v = *(const float4*)&((const float*)tokens)[k4];
        u16x4 o;
        o[0] = f2bf(v.x); o[1] = f2bf(v.y); o[2] = f2bf(v.z); o[3] = f2bf(v.w);
        *(u16x4*)&tokbf[k4] = o;
      }
    }
  } else if (bid < 5120) {
    int id = bid - 4096;
    int tensor = id >> 9, o = id & 511;
    const void* src = tensor ? w_wide : w_narrow;
    u16* dst = tensor ? wtW2 : wtN2;
    __shared__ u16 Ls[4608];
    for (int i = tid; i < 4608; i += 256) {
      Ls[i] = f ? f2bf(((const float*)src)[(size_t)o*4608 + i]) : ((const u16*)src)[(size_t)o*4608 + i];
    }
    __syncthreads();
    #pragma unroll
    for (int kk = 0; kk < 9; kk++) {
      #pragma unroll
      for (int u = 0; u < 2; u++) {
        int c = tid + u*256;
        dst[(size_t)kk*262144 + o*512 + c] = Ls[c*9 + kk];
      }
    }
  } else {
    int id = bid - 5120;
    int z = id / 192;
    int rem = id - z*192;
    int x = rem % 24, y = rem / 24;
    int Nn = (z == 0) ? 1536 : 512;
    if (x * 64 >= Nn) return;
    const void* src = (z == 0) ? w_qkv : (z == 1) ? w_out : ff_w;
    u16* dst = (z == 0) ? wqkvt : (z == 1) ? woutt : ffwt;
    __shared__ u16 Ts[64][72];
    int n0 = x * 64, k0 = y * 64;
    int r = tid >> 2, cq = (tid & 3) * 16;
    #pragma unroll
    for (int u = 0; u < 2; u++) {
      int c = cq + u*8;
      int sidx = (k0 + r)*Nn + n0 + c;
      u16x8 v;
      if (f) {
        #pragma unroll
        for (int j = 0; j < 8; j++) v[j] = f2bf(((const float*)src)[sidx + j]);
      } else {
        v = *(const u16x8*)&((const u16*)src)[sidx];
      }
      *(u16x8*)&Ts[r][c] = v;
    }
    __syncthreads();
    #pragma unroll
    for (int u = 0; u < 2; u++) {
      int c = cq + u*8;
      u16x8 v;
      #pragma unroll
      for (int j = 0; j < 8; j++) v[j] = Ts[c + j][r];
      *(u16x8*)&dst[(size_t)(n0 + r)*512 + k0 + c] = v;
    }
  }
}

// ---- qkv GEMM v3: 128x128 tile, gload_lds staging + XOR slot-swizzle, 2-barrier loop.
// A source selected at runtime: tokens directly when input already bf16 (skips tokbf copy).
__global__ __launch_bounds__(256) void mgemm_qkv_k(const void* tok_raw, const u16* tokbf,
                                                   const u16* Bt, const float* rope,
                                                   const int* mask, const int* flags,
                                                   u16* qb, u16* keb, u16* vb){
  __shared__ u16 As[128*32];
  __shared__ u16 Bs[128*32];
  __shared__ int smask[128];
  int tid = threadIdx.x;
  int lane = tid & 63;
  int wave = tid >> 6;
  int wm = (wave >> 1) * 64, wn = (wave & 1) * 64;
  int quad = lane >> 4, l16 = lane & 15;
  int m0 = blockIdx.y * 128, n0 = blockIdx.x * 128;
  const u16* A = flags[0] ? tokbf : (const u16*)tok_raw;
  fx4 acc[4][4] = {};
  for (int k0 = 0; k0 < 512; k0 += 32) {
    // stage A,B: 128 rows x 4 slots each; source slot-swizzled, LDS dest linear
    #pragma unroll
    for (int it = 0; it < 2; it++) {
      int s = it*256 + tid;
      int lsl = ((s & 3) ^ ((s >> 3) & 3)) * 8;
      gload16(&A[(size_t)(m0 + (s >> 2))*512 + k0 + lsl], &As[(it*256 + wave*64)*8]);
    }
    #pragma unroll
    for (int it = 0; it < 2; it++) {
      int s = it*256 + tid;
      int lsl = ((s & 3) ^ ((s >> 3) & 3)) * 8;
      gload16(&Bt[(size_t)(n0 + (s >> 2))*512 + k0 + lsl], &Bs[(it*256 + wave*64)*8]);
    }
    __syncthreads();   // vmcnt drain: tiles resident
    bf16x8 af[4], bfv[4];
    #pragma unroll
    for (int i = 0; i < 4; i++) {
      int row = wm + i*16 + l16;
      af[i] = __builtin_bit_cast(bf16x8,
                *(const u16x8*)&As[row*32 + ((quad ^ ((row >> 1) & 3)) * 8)]);
    }
    #pragma unroll
    for (int j = 0; j < 4; j++) {
      int row = wn + j*16 + l16;
      bfv[j] = __builtin_bit_cast(bf16x8,
                *(const u16x8*)&Bs[row*32 + ((quad ^ ((row >> 1) & 3)) * 8)]);
    }
    #pragma unroll
    for (int i = 0; i < 4; i++)
      #pragma unroll
      for (int j = 0; j < 4; j++)
        acc[i][j] = __builtin_amdgcn_mfma_f32_16x16x32_bf16(af[i], bfv[j], acc[i][j], 0, 0, 0);
    __syncthreads();   // readers done before next overwrite
  }
  int x = blockIdx.x;
  if (x >= 4) {
    if (tid < 128) smask[tid] = mask[m0 + tid];
    __syncthreads();
  }
  if (x < 4) {
    // q: softmax over d (64 cols = 4 regs x 16 lanes), scale 1/8, bf16 out
    #pragma unroll
    for (int i = 0; i < 4; i++)
      #pragma unroll
      for (int r = 0; r < 4; r++) {
        int rl = wm + i*16 + quad*4 + r;
        int row = m0 + rl;
        int nseq = row & (NN-1);
        const float* rp = rope + nseq*64 + l16;
        float e0 = __expf(acc[i][0][r] + rp[0]);
        float e1 = __expf(acc[i][1][r] + rp[16]);
        float e2 = __expf(acc[i][2][r] + rp[32]);
        float e3 = __expf(acc[i][3][r] + rp[48]);
        float s = e0 + e1 + e2 + e3;
        s += __shfl_xor(s, 1); s += __shfl_xor(s, 2);
        s += __shfl_xor(s, 4); s += __shfl_xor(s, 8);
        float sc = 0.125f / s;
        size_t base = (size_t)row*512 + n0 + wn + l16;
        qb[base]      = f2bf(e0*sc);
        qb[base + 16] = f2bf(e1*sc);
        qb[base + 32] = f2bf(e2*sc);
        qb[base + 48] = f2bf(e3*sc);
      }
  } else if (x < 8) {
    // k: ke = mask ? exp(k + rope) : 0 (bf16)
    #pragma unroll
    for (int i = 0; i < 4; i++)
      #pragma unroll
      for (int r = 0; r < 4; r++) {
        int rl = wm + i*16 + quad*4 + r;
        int row = m0 + rl;
        int nseq = row & (NN-1);
        int mk = smask[rl];
        const float* rp = rope + nseq*64 + l16;
        size_t base = (size_t)row*512 + (n0 - 512) + wn + l16;
        #pragma unroll
        for (int j = 0; j < 4; j++) {
          float ke = mk ? __expf(acc[i][j][r] + rp[j*16]) : 0.0f;
          keb[base + j*16] = f2bf(ke);
        }
      }
  } else {
    // v: masked bf16
    #pragma unroll
    for (int i = 0; i < 4; i++)
      #pragma unroll
      for (int r = 0; r < 4; r++) {
        int rl = wm + i*16 + quad*4 + r;
        int row = m0 + rl;
        int mk = smask[rl];
        size_t base = (size_t)row*512 + (n0 - 1024) + wn + l16;
        #pragma unroll
        for (int j = 0; j < 4; j++)
          vb[base + j*16] = mk ? f2bf(acc[i][j][r]) : (u16)0;
      }
  }
}

#define FMA16(a, b, acc) \
  acc[0][0] = fmaf(a.x, b.x, acc[0][0]); acc[0][1] = fmaf(a.x, b.y, acc[0][1]); \
  acc[0][2] = fmaf(a.x, b.z, acc[0][2]); acc[0][3] = fmaf(a.x, b.w, acc[0][3]); \
  acc[1][0] = fmaf(a.y, b.x, acc[1][0]); acc[1][1] = fmaf(a.y, b.y, acc[1][1]); \
  acc[1][2] = fmaf(a.y, b.z, acc[1][2]); acc[1][3] = fmaf(a.y, b.w, acc[1][3]); \
  acc[2][0] = fmaf(a.z, b.x, acc[2][0]); acc[2][1] = fmaf(a.z, b.y, acc[2][1]); \
  acc[2][2] = fmaf(a.z, b.z, acc[2][2]); acc[2][3] = fmaf(a.z, b.w, acc[2][3]); \
  acc[3][0] = fmaf(a.w, b.x, acc[3][0]); acc[3][1] = fmaf(a.w, b.y, acc[3][1]); \
  acc[3][2] = fmaf(a.w, b.z, acc[3][2]); acc[3][3] = fmaf(a.w, b.w, acc[3][3]);

// ctx[bh][d][e] += sum_n ke[n,d]*v[n,e] (bf16 inputs, exp/mask pre-applied); S[bh][d] += sum ke
// (R10 atomic version — restored after R11 partials rewrite regressed)
__global__ __launch_bounds__(256) void ctx_k(const u16* keb, const u16* vb, float* ctx, float* Sg){
  int bh = blockIdx.x, seg = blockIdx.y;
  int b = bh >> 3, h = bh & 7;
  __shared__ float Ks[32][68], Vs[32][68];
  __shared__ float sS[64];
  int tid = threadIdx.x, tx = tid & 15, ty = tid >> 4;
  if (tid < 64) sS[tid] = 0.0f;
  float acc[4][4] = {{0.f,0.f,0.f,0.f},{0.f,0.f,0.f,0.f},{0.f,0.f,0.f,0.f},{0.f,0.f,0.f,0.f}};
  float sp[8] = {0,0,0,0,0,0,0,0};
  int nl = tid >> 3, dcol = (tid & 7)*8;
  const u16* kp0 = keb + (size_t)(b*NN + seg*256)*512 + h*64 + dcol;
  const u16* vp0 = vb  + (size_t)(b*NN + seg*256)*512 + h*64 + dcol;
  for (int nc = 0; nc < 256; nc += 32) {
    u16x8 ku = *(const u16x8*)(kp0 + (size_t)(nc + nl)*512);
    u16x8 vu = *(const u16x8*)(vp0 + (size_t)(nc + nl)*512);
    float a[8], bb[8];
    #pragma unroll
    for (int t = 0; t < 8; t++) { a[t] = bf2f(ku[t]); bb[t] = bf2f(vu[t]); sp[t] += a[t]; }
    *(float4*)&Ks[nl][dcol]   = (float4){a[0],a[1],a[2],a[3]};
    *(float4*)&Ks[nl][dcol+4] = (float4){a[4],a[5],a[6],a[7]};
    *(float4*)&Vs[nl][dcol]   = (float4){bb[0],bb[1],bb[2],bb[3]};
    *(float4*)&Vs[nl][dcol+4] = (float4){bb[4],bb[5],bb[6],bb[7]};
    __syncthreads();
    #pragma unroll
    for (int q = 0; q < 32; q++) {
      float4 a4 = *(const float4*)&Ks[q][ty*4];
      float4 b4 = *(const float4*)&Vs[q][tx*4];
      FMA16(a4, b4, acc)
    }
    __syncthreads();
  }
  #pragma unroll
  for (int j = 0; j < 8; j++) atomicAdd(&sS[dcol + j], sp[j]);
  float* cp = ctx + (size_t)bh*4096;
  #pragma unroll
  for (int i = 0; i < 4; i++)
    #pragma unroll
    for (int j = 0; j < 4; j++)
      atomicAdd(&cp[(ty*4 + i)*64 + tx*4 + j], acc[i][j]);
  __syncthreads();
  if (tid < 64) atomicAdd(&Sg[bh*64 + tid], sS[tid]);
}

// merged: ctxw (blocks 0..31) + cpad-edge-zero (blocks 32..351)  (R10 version)
// W2t[b][o][h*64+d] = sum_e (ctx[b,h][d][e]/S[d]) * woutt[o][h*64+e]
__global__ __launch_bounds__(256) void ctxw_k(const float* ctx, const float* Sg, const u16* woutt,
                                              u16* W2t, u16* cpadb){
  int bx = blockIdx.x;
  int tid = threadIdx.x;
  if (bx >= 32) {
    int idx = (bx - 32)*256 + tid;
    if (idx < BB*40*512) {
      int c = idx & 511;
      int t = (idx >> 9) % 40;
      int b = idx / (40*512);
      int tt = (t < 20) ? t : 2048 + t;
      cpadb[((size_t)b*2088 + tt)*512 + c] = 0;
    }
    return;
  }
  int h = bx & 7, b = bx >> 3;
  int lane = tid & 63, wave = tid >> 6;
  int quad = lane >> 4, l16 = lane & 15;
  const float* cp = ctx + (size_t)(b*8 + h)*4096;
  fx4 acc[8][4] = {};
  #pragma unroll
  for (int ks = 0; ks < 2; ks++) {
    bf16x8 bfv[4];
    #pragma unroll
    for (int j = 0; j < 4; j++) {
      int d = j*16 + l16;
      float S = Sg[(b*8 + h)*64 + d];
      float rs = (S > 0.0f) ? 1.0f/S : 0.0f;
      const float* src = cp + d*64 + ks*32 + quad*8;
      float4 v0 = *(const float4*)src, v1 = *(const float4*)(src + 4);
      bf16x8 t;
      t[0]=(__bf16)(v0.x*rs); t[1]=(__bf16)(v0.y*rs); t[2]=(__bf16)(v0.z*rs); t[3]=(__bf16)(v0.w*rs);
      t[4]=(__bf16)(v1.x*rs); t[5]=(__bf16)(v1.y*rs); t[6]=(__bf16)(v1.z*rs); t[7]=(__bf16)(v1.w*rs);
      bfv[j] = t;
    }
    #pragma unroll
    for (int i = 0; i < 8; i++) {
      int orow = wave*128 + i*16 + l16;
      bf16x8 afr = __builtin_bit_cast(bf16x8, *(const u16x8*)&woutt[(size_t)orow*512 + h*64 + ks*32 + quad*8]);
      #pragma unroll
      for (int j = 0; j < 4; j++)
        acc[i][j] = __builtin_amdgcn_mfma_f32_16x16x32_bf16(afr, bfv[j], acc[i][j], 0, 0, 0);
    }
  }
  u16* out = W2t + (size_t)b*262144;
  #pragma unroll
  for (int i = 0; i < 8; i++)
    #pragma unroll
    for (int j = 0; j < 4; j++)
      #pragma unroll
      for (int r = 0; r < 4; r++) {
        int orow = wave*128 + i*16 + quad*4 + r;
        out[(size_t)orow*512 + h*64 + j*16 + l16] = f2bf(acc[i][j][r]);
      }
}

// ---- batched attn GEMM (M-tile 64): attnb = bf16(qb[b] @ W2t[b]^T + b_out); fused masked cpad ----
// VALU-staged (v13): M-tile-64 has too little compute/chunk to cover a serial vmcnt drain.
__global__ __launch_bounds__(256) void mgemm_attn64_k(const u16* qb, const u16* W2t, const float* bias,
                                                      const int* mask, u16* attnb, u16* cpadb){
  __shared__ u16 As[64][40];
  __shared__ u16 Bs[128][40];
  int tid = threadIdx.x;
  int lane = tid & 63;
  int wave = tid >> 6;
  int wn = wave * 32;
  int quad = lane >> 4, l16 = lane & 15;
  int m0 = blockIdx.y * 64, n0 = blockIdx.x * 128, b = blockIdx.z;
  const u16* A  = qb  + (size_t)b*2048*512;
  const u16* Bt = W2t + (size_t)b*262144;
  fx4 acc[4][2] = {};
  int ar = tid >> 2;
  int ac = (tid & 3) * 8;
  for (int k0 = 0; k0 < 512; k0 += 32) {
    *(u16x8*)&As[ar][ac]    = *(const u16x8*)&A[(size_t)(m0+ar)*512 + k0 + ac];
    *(u16x8*)&Bs[ar][ac]    = *(const u16x8*)&Bt[(size_t)(n0+ar)*512 + k0 + ac];
    *(u16x8*)&Bs[ar+64][ac] = *(const u16x8*)&Bt[(size_t)(n0+ar+64)*512 + k0 + ac];
    __syncthreads();
    bf16x8 af[4], bfv[2];
    #pragma unroll
    for (int i = 0; i < 4; i++)
      af[i] = __builtin_bit_cast(bf16x8, *(const u16x8*)&As[i*16 + l16][quad*8]);
    #pragma unroll
    for (int j = 0; j < 2; j++)
      bfv[j] = __builtin_bit_cast(bf16x8, *(const u16x8*)&Bs[wn + j*16 + l16][quad*8]);
    #pragma unroll
    for (int i = 0; i < 4; i++)
      #pragma unroll
      for (int j = 0; j < 2; j++)
        acc[i][j] = __builtin_amdgcn_mfma_f32_16x16x32_bf16(af[i], bfv[j], acc[i][j], 0, 0, 0);
    __syncthreads();
  }
  #pragma unroll
  for (int i = 0; i < 4; i++)
    #pragma unroll
    for (int j = 0; j < 2; j++) {
      int col = n0 + wn + j*16 + l16;
      float bv = bias[col];
      #pragma unroll
      for (int r = 0; r < 4; r++) {
        int row_l = m0 + i*16 + quad*4 + r;
        float v = acc[i][j][r] + bv;
        u16 vbb = f2bf(v);
        attnb[((size_t)b*2048 + row_l)*512 + col] = vbb;
        int mk = mask[b*2048 + row_l];
        cpadb[((size_t)b*2088 + row_l + 20)*512 + col] = mk ? vbb : (u16)0;
      }
    }
}

// ---- conv v15 (measured ~74us, declared structure-bound): v13 schedule, hoisted addrs ----
#define A_ROWS 552
#define A_SZ (A_ROWS*32)    // u16 units
#define W_SZ (9*64*32)
__global__ __launch_bounds__(512, 2) void mconv15_k(const u16* cpad, const u16* Wn, const u16* Ww,
                                                    const float* bias_n, const float* bias_w,
                                                    u16* Dn, u16* Dw){
  __shared__ u16 As[2*A_SZ];      // rows of 64B, slot-swizzled content
  __shared__ u16 Ws[2*W_SZ];      // [kk][o] rows of 64B, slot-swizzled content
  int tid = threadIdx.x;
  int lane = tid & 63;
  int wave = tid >> 6;            // 0..7
  int wm = wave * 64;             // t-offset within 512
  int quad = lane >> 4, l16 = lane & 15;
  int o0 = blockIdx.x * 64, m0 = blockIdx.y * 512;
  int b = blockIdx.z >> 1, cid = blockIdx.z & 1;
  const u16* W = cid ? Ww : Wn;
  const float* bias = cid ? bias_w : bias_n;
  u16* D = cid ? Dw : Dn;
  fx4 acc[4][4] = {};
  const u16* cb = cpad + ((size_t)b*2088 + m0)*512;
  int wslot = ((quad ^ ((l16 >> 1) & 3)) * 8);
  int sbase = cid ? 0 : 16;
  int sstep = cid ? 5 : 1;
  int rowb0 = sbase + wm + l16;

  const u16* ap[5]; bool av[5];
  #pragma unroll
  for (int it = 0; it < 5; it++) {
    int s = it*512 + tid;
    av[it] = (s < 2208);
    int row = av[it] ? (s >> 2) : 0;
    int lsl = ((s & 3) ^ ((s >> 3) & 3)) * 8;
    ap[it] = cb + (size_t)row*512 + lsl;
  }
  const u16* wp[5]; bool wv[5];
  #pragma unroll
  for (int it = 0; it < 5; it++) {
    int s = it*512 + tid;
    wv[it] = (s < 2304);
    int kk = wv[it] ? (s >> 8) : 0;
    int ow = (s >> 2) & 63;
    int lsl = ((s & 3) ^ ((s >> 3) & 3)) * 8;
    wp[it] = W + (size_t)kk*262144 + (size_t)(o0 + ow)*512 + lsl;
  }

#define STAGE_CHUNK(c0, buf)                                                          \
  {                                                                                   \
    _Pragma("unroll")                                                                 \
    for (int it = 0; it < 5; it++) {                                                  \
      if (av[it])                                                                     \
        gload16(ap[it] + (c0), &As[(buf)*A_SZ + (it*512 + wave*64)*8]);               \
    }                                                                                 \
    _Pragma("unroll")                                                                 \
    for (int it = 0; it < 5; it++) {                                                  \
      if (wv[it])                                                                     \
        gload16(wp[it] + (c0), &Ws[(buf)*W_SZ + (it*512 + wave*64)*8]);               \
    }                                                                                 \
  }

#define LOADFRAG(kk, bfv, afr)                                                        \
  {                                                                                   \
    int rowb = rowb0 + sstep*(kk);                                                    \
    int aslot = ((quad ^ ((rowb >> 1) & 3)) * 8);                                     \
    _Pragma("unroll")                                                                 \
    for (int j = 0; j < 4; j++)                                                       \
      bfv[j] = __builtin_bit_cast(bf16x8,                                             \
                 *(const u16x8*)&Wsb[((kk)*64 + j*16 + l16)*32 + wslot]);             \
    _Pragma("unroll")                                                                 \
    for (int i = 0; i < 4; i++)                                                       \
      afr[i] = __builtin_bit_cast(bf16x8,                                             \
                 *(const u16x8*)&Asb[(rowb + i*16)*32 + aslot]);                      \
  }

#define MFMATAP_SGB(bfv, afr)                                                         \
  {                                                                                   \
    _Pragma("unroll")                                                                 \
    for (int i = 0; i < 4; i++)                                                       \
      _Pragma("unroll")                                                               \
      for (int j = 0; j < 4; j++)                                                     \
        acc[i][j] = __builtin_amdgcn_mfma_f32_16x16x32_bf16(afr[i], bfv[j],           \
                                                            acc[i][j], 0, 0, 0);      \
    _Pragma("unroll")                                                                 \
    for (int g = 0; g < 8; g++) {                                                     \
      __builtin_amdgcn_sched_group_barrier(0x008, 2, 0);  /* 2 MFMA */                \
      __builtin_amdgcn_sched_group_barrier(0x100, 1, 0);  /* 1 DS_READ */             \
    }                                                                                 \
  }

#define MFMATAP_PLAIN(bfv, afr)                                                       \
  {                                                                                   \
    _Pragma("unroll")                                                                 \
    for (int i = 0; i < 4; i++)                                                       \
      _Pragma("unroll")                                                               \
      for (int j = 0; j < 4; j++)                                                     \
        acc[i][j] = __builtin_amdgcn_mfma_f32_16x16x32_bf16(afr[i], bfv[j],           \
                                                            acc[i][j], 0, 0, 0);      \
  }

  STAGE_CHUNK(0, 0)
  __syncthreads();

  for (int ch = 0; ch < 16; ch++) {
    int cur = ch & 1;
    const u16* Asb = &As[cur*A_SZ];
    const u16* Wsb = &Ws[cur*W_SZ];
    bf16x8 bfvA[4], afrA[4], bfvB[4], afrB[4];
    LOADFRAG(0, bfvA, afrA)
    if (ch < 15) {
      int c0n = (ch + 1) * 32;
      int nb = cur ^ 1;
      STAGE_CHUNK(c0n, nb)
    }
    #pragma unroll
    for (int kt = 0; kt < 8; kt += 2) {
      LOADFRAG(kt+1, bfvB, afrB)
      MFMATAP_SGB(bfvA, afrA)
      LOADFRAG(kt+2, bfvA, afrA)
      MFMATAP_SGB(bfvB, afrB)
    }
    MFMATAP_PLAIN(bfvA, afrA)
    __syncthreads();
  }
#undef STAGE_CHUNK
#undef LOADFRAG
#undef MFMATAP_SGB
#undef MFMATAP_PLAIN
  #pragma unroll
  for (int i = 0; i < 4; i++)
    #pragma unroll
    for (int j = 0; j < 4; j++) {
      int col = o0 + j*16 + l16;
      float bv = bias[col];
      #pragma unroll
      for (int r = 0; r < 4; r++) {
        int row = b*2048 + m0 + wm + i*16 + quad*4 + r;
        D[(size_t)row*512 + col] = f2bf(geluf(acc[i][j][r] + bv));
      }
    }
}

// ---- ff GEMM v2: 128x128 tile, 512 threads, gload_lds staging + XOR swizzle ----
__global__ __launch_bounds__(512) void mgemm128b_k(const u16* A, const u16* Bt, const float* bias,
                                                   u16* C){
  __shared__ u16 As[128*32];
  __shared__ u16 Bs[128*32];
  int tid = threadIdx.x;
  int lane = tid & 63;
  int wave = tid >> 6;          // 0..7
  int wm = (wave >> 2) * 64;    // 0 or 64
  int wn = (wave & 3) * 32;     // 0,32,64,96
  int quad = lane >> 4, l16 = lane & 15;
  int m0 = blockIdx.y * 128, n0 = blockIdx.x * 128;
  fx4 acc[4][2] = {};
  for (int k0 = 0; k0 < 512; k0 += 32) {
    {
      int s = tid;
      int lsl = ((s & 3) ^ ((s >> 3) & 3)) * 8;
      gload16(&A[(size_t)(m0 + (s >> 2))*512 + k0 + lsl], &As[(wave*64)*8]);
    }
    {
      int s = tid;
      int lsl = ((s & 3) ^ ((s >> 3) & 3)) * 8;
      gload16(&Bt[(size_t)(n0 + (s >> 2))*512 + k0 + lsl], &Bs[(wave*64)*8]);
    }
    __syncthreads();
    bf16x8 af[4], bfv[2];
    #pragma unroll
    for (int i = 0; i < 4; i++) {
      int row = wm + i*16 + l16;
      af[i] = __builtin_bit_cast(bf16x8,
                *(const u16x8*)&As[row*32 + ((quad ^ ((row >> 1) & 3)) * 8)]);
    }
    #pragma unroll
    for (int j = 0; j < 2; j++) {
      int row = wn + j*16 + l16;
      bfv[j] = __builtin_bit_cast(bf16x8,
                *(const u16x8*)&Bs[row*32 + ((quad ^ ((row >> 1) & 3)) * 8)]);
    }
    #pragma unroll
    for (int i = 0; i < 4; i++)
      #pragma unroll
      for (int j = 0; j < 2; j++)
        acc[i][j] = __builtin_amdgcn_mfma_f32_16x16x32_bf16(af[i], bfv[j], acc[i][j], 0, 0, 0);
    __syncthreads();
  }
  #pragma unroll
  for (int i = 0; i < 4; i++)
    #pragma unroll
    for (int j = 0; j < 2; j++) {
      int col = n0 + wn + j*16 + l16;
      float bv = bias[col];
      #pragma unroll
      for (int r = 0; r < 4; r++) {
        int row = m0 + wm + i*16 + quad*4 + r;
        C[(size_t)row*512 + col] = f2bf(geluf(acc[i][j][r] + bv));
      }
    }
}

// LN wave-per-row: 4 rows/block (one per wave), u16x8 loads (8 elems/lane), pure
// shfl_xor reduction — no barriers, no LDS. NADD extra inputs; OM as before.
template<int NADD, int OM>
__global__ __launch_bounds__(256) void lnw_k(const u16* X, const u16* Y, const u16* Z,
                                             const float* g, const float* be,
                                             const int* flags, void* out){
  int wave = threadIdx.x >> 6, lane = threadIdx.x & 63;
  size_t row = (size_t)blockIdx.x*4 + wave;
  int c = lane*8;
  float x[8];
  {
    u16x8 xv = *(const u16x8*)&X[row*512 + c];
    #pragma unroll
    for (int t = 0; t < 8; t++) x[t] = bf2f(xv[t]);
  }
  if (NADD >= 1) {
    u16x8 yv = *(const u16x8*)&Y[row*512 + c];
    #pragma unroll
    for (int t = 0; t < 8; t++) x[t] += bf2f(yv[t]);
  }
  if (NADD >= 2) {
    u16x8 zv = *(const u16x8*)&Z[row*512 + c];
    #pragma unroll
    for (int t = 0; t < 8; t++) x[t] += bf2f(zv[t]);
  }
  float s = 0.0f;
  #pragma unroll
  for (int t = 0; t < 8; t++) s += x[t];
  #pragma unroll
  for (int o = 32; o; o >>= 1) s += __shfl_xor(s, o, 64);
  float mean = s * (1.0f/512.0f);
  float d[8], s2 = 0.0f;
  #pragma unroll
  for (int t = 0; t < 8; t++) { d[t] = x[t] - mean; s2 += d[t]*d[t]; }
  #pragma unroll
  for (int o = 32; o; o >>= 1) s2 += __shfl_xor(s2, o, 64);
  float inv = rsqrtf(s2 * (1.0f/512.0f) + 1e-5f);
  float4 g0 = *(const float4*)&g[c],  g1 = *(const float4*)&g[c+4];
  float4 b0 = *(const float4*)&be[c], b1 = *(const float4*)&be[c+4];
  float r[8];
  r[0] = d[0]*inv*g0.x + b0.x; r[1] = d[1]*inv*g0.y + b0.y;
  r[2] = d[2]*inv*g0.z + b0.z; r[3] = d[3]*inv*g0.w + b0.w;
  r[4] = d[4]*inv*g1.x + b1.x; r[5] = d[5]*inv*g1.y + b1.y;
  r[6] = d[6]*inv*g1.z + b1.z; r[7] = d[7]*inv*g1.w + b1.w;
  bool obf = (OM == 1) || (OM == 2 && !flags[0]);
  if (obf) {
    u16x8 ov;
    #pragma unroll
    for (int t = 0; t < 8; t++) ov[t] = f2bf(r[t]);
    *(u16x8*)&((u16*)out)[row*512 + c] = ov;
  } else {
    float* op = (float*)out + row*512 + c;
    *(float4*)op       = (float4){r[0], r[1], r[2], r[3]};
    *(float4*)(op + 4) = (float4){r[4], r[5], r[6], r[7]};
  }
}

extern "C" void kernel_launch(void* const* d_in, const int* in_sizes, int n_in,
                              void* d_out, int out_size, void* d_ws, size_t ws_size,
                              hipStream_t stream) {
  const void* tokens   = d_in[0];
  const void* mask     = d_in[1];
  const void* w_qkv    = d_in[2];
  const void* w_out    = d_in[3];
  const void* b_out    = d_in[4];
  const void* w_narrow = d_in[5];
  const void* b_narrow = d_in[6];
  const void* w_wide   = d_in[7];
  const void* b_wide   = d_in[8];
  const void* ln1_g    = d_in[9];
  const void* ln1_b    = d_in[10];
  const void* ff_w     = d_in[11];
  const void* ff_b     = d_in[12];
  const void* ln2_g    = d_in[13];
  const void* ln2_b    = d_in[14];

  float* ws = (float*)d_ws;
  int*   flags  = (int*)ws;                    // 16
  int*   m32    = (int*)(ws + 16);             // 8192 -> 8208
  float* params = ws + 8208;                   // 4096 -> 12304
  float* kS     = ws + 12304;                  // 2048 -> 14352
  float* ctx    = ws + 14352;                  // 131072 -> 145424
  float* rope   = ws + 145424;                 // 131072 -> 276496
  u16*   tokbf  = (u16*)(ws + 276496);         // 4194304 u16 -> 2373648
  u16*   wqkvt  = (u16*)(ws + 2373648);        // 786432 u16 -> 2766864
  u16*   woutt  = (u16*)(ws + 2766864);        // 262144 u16 -> 2897936
  u16*   ffwt   = (u16*)(ws + 2897936);        // 262144 u16 -> 3029008
  u16*   wtN2   = (u16*)(ws + 3029008);        // 2359296 u16 -> 4208656
  u16*   wtW2   = (u16*)(ws + 4208656);        // 2359296 u16 -> 5388304
  u16*   qb     = (u16*)(ws + 5388304);        // 4194304 u16 -> 7485456
  u16*   keb    = (u16*)(ws + 7485456);        // 4194304 u16 -> 9582608
  u16*   vb     = (u16*)(ws + 9582608);        // 4194304 u16 -> 11679760
  u16*   W2t    = (u16*)(ws + 11679760);       // 1048576 u16 -> 12204048
  u16*   attnb  = (u16*)(ws + 12204048);       // 4194304 u16 -> 14301200
  u16*   cpadb  = (u16*)(ws + 14301200);       // 4276224 u16 -> 16439312
  u16*   Dnb    = (u16*)(ws + 16439312);       // 4194304 u16 -> 18536464
  u16*   Dwb    = (u16*)(ws + 18536464);       // 4194304 u16 -> 20633616 (~82.5 MB)
  u16*   Eb     = attnb;                       // attnb dead after ln1
  u16*   t1b    = tokbf;                       // tokbf dead after qkv gemm

  float* p_bout = params;        float* p_bnar = params + 512;
  float* p_bwid = params + 1024; float* p_l1g  = params + 1536;
  float* p_l1b  = params + 2048; float* p_ffb  = params + 2560;
  float* p_l2g  = params + 3072; float* p_l2b  = params + 3584;

  sniff_k<<<dim3(1), dim3(256), 0, stream>>>((const u16*)tokens, (const unsigned int*)mask, flags);

  // merged preprocessing: misc (4096) + conv weight prep (1024) + transpose (576)
  misc2_k<<<dim3(5696), dim3(256), 0, stream>>>(mask, tokens, b_out, b_narrow, b_wide, ln1_g, ln1_b,
                                                ff_b, ln2_g, ln2_b, flags, rope, m32, params, ctx,
                                                kS, tokbf, w_qkv, w_out, ff_w, w_narrow, w_wide,
                                                wqkvt, woutt, ffwt, wtN2, wtW2);

  // qkv GEMM; A = tokens directly when input already bf16 (tokbf only on f32 path)
  mgemm_qkv_k<<<dim3(12, 64), dim3(256), 0, stream>>>(
      tokens, tokbf, wqkvt, rope, m32, flags, qb, keb, vb);

  // ctx = ke^T @ v (+ S accumulation), atomic version (R10)
  ctx_k<<<dim3(32, 8), dim3(256), 0, stream>>>(keb, vb, ctx, kS);

  // W2t[b] = (blockdiag(ctx_b)/S) @ w_out; + cpad edge zero
  ctxw_k<<<dim3(352), dim3(256), 0, stream>>>(ctx, kS, woutt, W2t, cpadb);

  // attn = qb @ W2t[b]^T + b_out (bf16); fused masked cpad write
  mgemm_attn64_k<<<dim3(4, 32, 4), dim3(256), 0, stream>>>(qb, W2t, p_bout, m32, attnb, cpadb);

  // convs: v13 schedule + hoisted staging addresses
  mconv15_k<<<dim3(8, 4, 8), dim3(512), 0, stream>>>(cpadb, wtN2, wtW2, p_bnar, p_bwid, Dnb, Dwb);

  // t1 = LN(attn + Dn + Dw) -> bf16 (wave-per-row)
  lnw_k<2,1><<<dim3(NROWS/4), dim3(256), 0, stream>>>(attnb, Dnb, Dwb, p_l1g, p_l1b, flags, (void*)t1b);

  // E = gelu(t1 @ ff_w + ff_b) -> bf16
  mgemm128b_k<<<dim3(4, 64), dim3(512), 0, stream>>>(t1b, ffwt, p_ffb, Eb);

  // out = LN(E) -> d_out, dtype per flags (wave-per-row)
  lnw_k<0,2><<<dim3(NROWS/4), dim3(256), 0, stream>>>(Eb, nullptr, nullptr, p_l2g, p_l2b, flags, d_out);
}

// Round 13
// 308.293 us; speedup vs baseline: 1.2215x; 1.2215x over previous
//
#include <hip/hip_runtime.h>
#include <hip/hip_bf16.h>

#define BB 4
#define NN 2048
#define NROWS (BB*NN)   // 8192

typedef unsigned short u16;
typedef __bf16 bf16x8 __attribute__((ext_vector_type(8)));
typedef u16    u16x8  __attribute__((ext_vector_type(8)));
typedef u16    u16x4  __attribute__((ext_vector_type(4)));
typedef float  fx4    __attribute__((ext_vector_type(4)));

__device__ __forceinline__ float bf2f(u16 u){
  union { float f; unsigned int i; } x; x.i = ((unsigned int)u) << 16; return x.f;
}
__device__ __forceinline__ u16 f2bf(float f){
  union { float f; unsigned int i; } x; x.f = f;
  unsigned int i = x.i;
  i += 0x7fffu + ((i >> 16) & 1u);
  return (u16)(i >> 16);
}
__device__ __forceinline__ float geluf(float x){
  return 0.5f * x * (1.0f + erff(x * 0.70710678118654752f));
}
__device__ __forceinline__ void gload16(const void* g, void* l){
  __builtin_amdgcn_global_load_lds((const __attribute__((address_space(1))) unsigned int*)g,
                                   (__attribute__((address_space(3))) unsigned int*)l, 16, 0, 0);
}

// flags[0]=1 if float inputs fp32 (else bf16); flags[1]=1 if mask byte-packed
__global__ __launch_bounds__(256) void sniff_k(const u16* tokens, const unsigned int* mask, int* flags){
  __shared__ int s_f32, s_byte;
  if (threadIdx.x == 0) { s_f32 = 0; s_byte = 0; }
  __syncthreads();
  for (int i = threadIdx.x; i < 4096; i += 256) {
    float v = bf2f(tokens[i]);
    if (!(fabsf(v) < 1e10f)) atomicOr(&s_f32, 1);
  }
  for (int i = threadIdx.x; i < 2048; i += 256) {
    if (mask[i] > 1u) atomicOr(&s_byte, 1);
  }
  __syncthreads();
  if (threadIdx.x == 0) { flags[0] = s_f32; flags[1] = s_byte; }
}

// merged: blocks [0,4096): rope + m32 + params + zero(ctx,kS) + tokbf(f32-only, x4) grid-stride;
// blocks [4096,5120): conv weights w[o][c][kk] -> W2[kk][o][c];
// blocks [5120,5696): LDS tile transpose [K][N]->[N][K] for the three dense weights
__global__ __launch_bounds__(256) void misc2_k(const void* mask, const void* tokens,
                                               const void* p0, const void* p1, const void* p2,
                                               const void* p3, const void* p4, const void* p5,
                                               const void* p6, const void* p7,
                                               const int* flags, float* rope, int* m32,
                                               float* params, float* ctx, float* kS, u16* tokbf,
                                               const void* w_qkv, const void* w_out, const void* ff_w,
                                               const void* w_narrow, const void* w_wide,
                                               u16* wqkvt, u16* woutt, u16* ffwt,
                                               u16* wtN2, u16* wtW2){
  int bid = blockIdx.x;
  int tid = threadIdx.x;
  int f = flags[0];
  if (bid < 4096) {
    const void* srcs[8] = {p0,p1,p2,p3,p4,p5,p6,p7};
    int mbyte = flags[1];
    const int T = 276480 + 1048576;   // ...+ tokbf handled x4 (f32 path only)
    for (int i = bid*256 + tid; i < T; i += 4096*256) {
      if (i < 131072) {
        int p = i >> 6, j = i & 63;
        int jj = (j < 32) ? j : j - 32;
        float invf = exp2f(-(float)jj * (13.287712379549449f/32.0f));  // 10000^(-jj/32)
        float prod = (float)p * invf;
        rope[i] = (j < 32) ? sinf(prod) : cosf(prod);
      } else if (i < 139264) {
        int k = i - 131072;
        int v = mbyte ? (int)((const unsigned char*)mask)[k] : ((const int*)mask)[k];
        m32[k] = v ? 1 : 0;
      } else if (i < 143360) {
        int k = i - 139264;
        int pid = k >> 9, j = k & 511;
        const void* s = srcs[pid];
        params[k] = f ? ((const float*)s)[j] : bf2f(((const u16*)s)[j]);
      } else if (i < 274432) {
        ctx[i - 143360] = 0.0f;
      } else if (i < 276480) {
        kS[i - 274432] = 0.0f;
      } else if (f) {
        // fp32 input: convert tokens -> bf16 tokbf, 4 elems per item
        int k4 = (i - 276480) * 4;
        float4 v = *(const float4*)&((const float*)tokens)[k4];
        u16x4 o;
        o[0] = f2bf(v.x); o[1] = f2bf(v.y); o[2] = f2bf(v.z); o[3] = f2bf(v.w);
        *(u16x4*)&tokbf[k4] = o;
      }
    }
  } else if (bid < 5120) {
    int id = bid - 4096;
    int tensor = id >> 9, o = id & 511;
    const void* src = tensor ? w_wide : w_narrow;
    u16* dst = tensor ? wtW2 : wtN2;
    __shared__ u16 Ls[4608];
    for (int i = tid; i < 4608; i += 256) {
      Ls[i] = f ? f2bf(((const float*)src)[(size_t)o*4608 + i]) : ((const u16*)src)[(size_t)o*4608 + i];
    }
    __syncthreads();
    #pragma unroll
    for (int kk = 0; kk < 9; kk++) {
      #pragma unroll
      for (int u = 0; u < 2; u++) {
        int c = tid + u*256;
        dst[(size_t)kk*262144 + o*512 + c] = Ls[c*9 + kk];
      }
    }
  } else {
    int id = bid - 5120;
    int z = id / 192;
    int rem = id - z*192;
    int x = rem % 24, y = rem / 24;
    int Nn = (z == 0) ? 1536 : 512;
    if (x * 64 >= Nn) return;
    const void* src = (z == 0) ? w_qkv : (z == 1) ? w_out : ff_w;
    u16* dst = (z == 0) ? wqkvt : (z == 1) ? woutt : ffwt;
    __shared__ u16 Ts[64][72];
    int n0 = x * 64, k0 = y * 64;
    int r = tid >> 2, cq = (tid & 3) * 16;
    #pragma unroll
    for (int u = 0; u < 2; u++) {
      int c = cq + u*8;
      int sidx = (k0 + r)*Nn + n0 + c;
      u16x8 v;
      if (f) {
        #pragma unroll
        for (int j = 0; j < 8; j++) v[j] = f2bf(((const float*)src)[sidx + j]);
      } else {
        v = *(const u16x8*)&((const u16*)src)[sidx];
      }
      *(u16x8*)&Ts[r][c] = v;
    }
    __syncthreads();
    #pragma unroll
    for (int u = 0; u < 2; u++) {
      int c = cq + u*8;
      u16x8 v;
      #pragma unroll
      for (int j = 0; j < 8; j++) v[j] = Ts[c + j][r];
      *(u16x8*)&dst[(size_t)(n0 + r)*512 + k0 + c] = v;
    }
  }
}

// ---- qkv GEMM v3: 128x128 tile, gload_lds staging + XOR slot-swizzle, 2-barrier loop.
// A source selected at runtime: tokens directly when input already bf16 (skips tokbf copy).
__global__ __launch_bounds__(256) void mgemm_qkv_k(const void* tok_raw, const u16* tokbf,
                                                   const u16* Bt, const float* rope,
                                                   const int* mask, const int* flags,
                                                   u16* qb, u16* keb, u16* vb){
  __shared__ u16 As[128*32];
  __shared__ u16 Bs[128*32];
  __shared__ int smask[128];
  int tid = threadIdx.x;
  int lane = tid & 63;
  int wave = tid >> 6;
  int wm = (wave >> 1) * 64, wn = (wave & 1) * 64;
  int quad = lane >> 4, l16 = lane & 15;
  int m0 = blockIdx.y * 128, n0 = blockIdx.x * 128;
  const u16* A = flags[0] ? tokbf : (const u16*)tok_raw;
  fx4 acc[4][4] = {};
  for (int k0 = 0; k0 < 512; k0 += 32) {
    // stage A,B: 128 rows x 4 slots each; source slot-swizzled, LDS dest linear
    #pragma unroll
    for (int it = 0; it < 2; it++) {
      int s = it*256 + tid;
      int lsl = ((s & 3) ^ ((s >> 3) & 3)) * 8;
      gload16(&A[(size_t)(m0 + (s >> 2))*512 + k0 + lsl], &As[(it*256 + wave*64)*8]);
    }
    #pragma unroll
    for (int it = 0; it < 2; it++) {
      int s = it*256 + tid;
      int lsl = ((s & 3) ^ ((s >> 3) & 3)) * 8;
      gload16(&Bt[(size_t)(n0 + (s >> 2))*512 + k0 + lsl], &Bs[(it*256 + wave*64)*8]);
    }
    __syncthreads();   // vmcnt drain: tiles resident
    bf16x8 af[4], bfv[4];
    #pragma unroll
    for (int i = 0; i < 4; i++) {
      int row = wm + i*16 + l16;
      af[i] = __builtin_bit_cast(bf16x8,
                *(const u16x8*)&As[row*32 + ((quad ^ ((row >> 1) & 3)) * 8)]);
    }
    #pragma unroll
    for (int j = 0; j < 4; j++) {
      int row = wn + j*16 + l16;
      bfv[j] = __builtin_bit_cast(bf16x8,
                *(const u16x8*)&Bs[row*32 + ((quad ^ ((row >> 1) & 3)) * 8)]);
    }
    #pragma unroll
    for (int i = 0; i < 4; i++)
      #pragma unroll
      for (int j = 0; j < 4; j++)
        acc[i][j] = __builtin_amdgcn_mfma_f32_16x16x32_bf16(af[i], bfv[j], acc[i][j], 0, 0, 0);
    __syncthreads();   // readers done before next overwrite
  }
  int x = blockIdx.x;
  if (x >= 4) {
    if (tid < 128) smask[tid] = mask[m0 + tid];
    __syncthreads();
  }
  if (x < 4) {
    // q: softmax over d (64 cols = 4 regs x 16 lanes), scale 1/8, bf16 out
    #pragma unroll
    for (int i = 0; i < 4; i++)
      #pragma unroll
      for (int r = 0; r < 4; r++) {
        int rl = wm + i*16 + quad*4 + r;
        int row = m0 + rl;
        int nseq = row & (NN-1);
        const float* rp = rope + nseq*64 + l16;
        float e0 = __expf(acc[i][0][r] + rp[0]);
        float e1 = __expf(acc[i][1][r] + rp[16]);
        float e2 = __expf(acc[i][2][r] + rp[32]);
        float e3 = __expf(acc[i][3][r] + rp[48]);
        float s = e0 + e1 + e2 + e3;
        s += __shfl_xor(s, 1); s += __shfl_xor(s, 2);
        s += __shfl_xor(s, 4); s += __shfl_xor(s, 8);
        float sc = 0.125f / s;
        size_t base = (size_t)row*512 + n0 + wn + l16;
        qb[base]      = f2bf(e0*sc);
        qb[base + 16] = f2bf(e1*sc);
        qb[base + 32] = f2bf(e2*sc);
        qb[base + 48] = f2bf(e3*sc);
      }
  } else if (x < 8) {
    // k: ke = mask ? exp(k + rope) : 0 (bf16)
    #pragma unroll
    for (int i = 0; i < 4; i++)
      #pragma unroll
      for (int r = 0; r < 4; r++) {
        int rl = wm + i*16 + quad*4 + r;
        int row = m0 + rl;
        int nseq = row & (NN-1);
        int mk = smask[rl];
        const float* rp = rope + nseq*64 + l16;
        size_t base = (size_t)row*512 + (n0 - 512) + wn + l16;
        #pragma unroll
        for (int j = 0; j < 4; j++) {
          float ke = mk ? __expf(acc[i][j][r] + rp[j*16]) : 0.0f;
          keb[base + j*16] = f2bf(ke);
        }
      }
  } else {
    // v: masked bf16
    #pragma unroll
    for (int i = 0; i < 4; i++)
      #pragma unroll
      for (int r = 0; r < 4; r++) {
        int rl = wm + i*16 + quad*4 + r;
        int row = m0 + rl;
        int mk = smask[rl];
        size_t base = (size_t)row*512 + (n0 - 1024) + wn + l16;
        #pragma unroll
        for (int j = 0; j < 4; j++)
          vb[base + j*16] = mk ? f2bf(acc[i][j][r]) : (u16)0;
      }
  }
}

#define FMA16(a, b, acc) \
  acc[0][0] = fmaf(a.x, b.x, acc[0][0]); acc[0][1] = fmaf(a.x, b.y, acc[0][1]); \
  acc[0][2] = fmaf(a.x, b.z, acc[0][2]); acc[0][3] = fmaf(a.x, b.w, acc[0][3]); \
  acc[1][0] = fmaf(a.y, b.x, acc[1][0]); acc[1][1] = fmaf(a.y, b.y, acc[1][1]); \
  acc[1][2] = fmaf(a.y, b.z, acc[1][2]); acc[1][3] = fmaf(a.y, b.w, acc[1][3]); \
  acc[2][0] = fmaf(a.z, b.x, acc[2][0]); acc[2][1] = fmaf(a.z, b.y, acc[2][1]); \
  acc[2][2] = fmaf(a.z, b.z, acc[2][2]); acc[2][3] = fmaf(a.z, b.w, acc[2][3]); \
  acc[3][0] = fmaf(a.w, b.x, acc[3][0]); acc[3][1] = fmaf(a.w, b.y, acc[3][1]); \
  acc[3][2] = fmaf(a.w, b.z, acc[3][2]); acc[3][3] = fmaf(a.w, b.w, acc[3][3]);

// ctx[bh][d][e] += sum_n ke[n,d]*v[n,e] (bf16 inputs, exp/mask pre-applied); S[bh][d] += sum ke
// (R10 atomic version)
__global__ __launch_bounds__(256) void ctx_k(const u16* keb, const u16* vb, float* ctx, float* Sg){
  int bh = blockIdx.x, seg = blockIdx.y;
  int b = bh >> 3, h = bh & 7;
  __shared__ float Ks[32][68], Vs[32][68];
  __shared__ float sS[64];
  int tid = threadIdx.x, tx = tid & 15, ty = tid >> 4;
  if (tid < 64) sS[tid] = 0.0f;
  float acc[4][4] = {{0.f,0.f,0.f,0.f},{0.f,0.f,0.f,0.f},{0.f,0.f,0.f,0.f},{0.f,0.f,0.f,0.f}};
  float sp[8] = {0,0,0,0,0,0,0,0};
  int nl = tid >> 3, dcol = (tid & 7)*8;
  const u16* kp0 = keb + (size_t)(b*NN + seg*256)*512 + h*64 + dcol;
  const u16* vp0 = vb  + (size_t)(b*NN + seg*256)*512 + h*64 + dcol;
  for (int nc = 0; nc < 256; nc += 32) {
    u16x8 ku = *(const u16x8*)(kp0 + (size_t)(nc + nl)*512);
    u16x8 vu = *(const u16x8*)(vp0 + (size_t)(nc + nl)*512);
    float a[8], bb[8];
    #pragma unroll
    for (int t = 0; t < 8; t++) { a[t] = bf2f(ku[t]); bb[t] = bf2f(vu[t]); sp[t] += a[t]; }
    *(float4*)&Ks[nl][dcol]   = (float4){a[0],a[1],a[2],a[3]};
    *(float4*)&Ks[nl][dcol+4] = (float4){a[4],a[5],a[6],a[7]};
    *(float4*)&Vs[nl][dcol]   = (float4){bb[0],bb[1],bb[2],bb[3]};
    *(float4*)&Vs[nl][dcol+4] = (float4){bb[4],bb[5],bb[6],bb[7]};
    __syncthreads();
    #pragma unroll
    for (int q = 0; q < 32; q++) {
      float4 a4 = *(const float4*)&Ks[q][ty*4];
      float4 b4 = *(const float4*)&Vs[q][tx*4];
      FMA16(a4, b4, acc)
    }
    __syncthreads();
  }
  #pragma unroll
  for (int j = 0; j < 8; j++) atomicAdd(&sS[dcol + j], sp[j]);
  float* cp = ctx + (size_t)bh*4096;
  #pragma unroll
  for (int i = 0; i < 4; i++)
    #pragma unroll
    for (int j = 0; j < 4; j++)
      atomicAdd(&cp[(ty*4 + i)*64 + tx*4 + j], acc[i][j]);
  __syncthreads();
  if (tid < 64) atomicAdd(&Sg[bh*64 + tid], sS[tid]);
}

// merged: ctxw (blocks 0..31) + cpad-edge-zero (blocks 32..351)  (R10 version)
// W2t[b][o][h*64+d] = sum_e (ctx[b,h][d][e]/S[d]) * woutt[o][h*64+e]
__global__ __launch_bounds__(256) void ctxw_k(const float* ctx, const float* Sg, const u16* woutt,
                                              u16* W2t, u16* cpadb){
  int bx = blockIdx.x;
  int tid = threadIdx.x;
  if (bx >= 32) {
    int idx = (bx - 32)*256 + tid;
    if (idx < BB*40*512) {
      int c = idx & 511;
      int t = (idx >> 9) % 40;
      int b = idx / (40*512);
      int tt = (t < 20) ? t : 2048 + t;
      cpadb[((size_t)b*2088 + tt)*512 + c] = 0;
    }
    return;
  }
  int h = bx & 7, b = bx >> 3;
  int lane = tid & 63, wave = tid >> 6;
  int quad = lane >> 4, l16 = lane & 15;
  const float* cp = ctx + (size_t)(b*8 + h)*4096;
  fx4 acc[8][4] = {};
  #pragma unroll
  for (int ks = 0; ks < 2; ks++) {
    bf16x8 bfv[4];
    #pragma unroll
    for (int j = 0; j < 4; j++) {
      int d = j*16 + l16;
      float S = Sg[(b*8 + h)*64 + d];
      float rs = (S > 0.0f) ? 1.0f/S : 0.0f;
      const float* src = cp + d*64 + ks*32 + quad*8;
      float4 v0 = *(const float4*)src, v1 = *(const float4*)(src + 4);
      bf16x8 t;
      t[0]=(__bf16)(v0.x*rs); t[1]=(__bf16)(v0.y*rs); t[2]=(__bf16)(v0.z*rs); t[3]=(__bf16)(v0.w*rs);
      t[4]=(__bf16)(v1.x*rs); t[5]=(__bf16)(v1.y*rs); t[6]=(__bf16)(v1.z*rs); t[7]=(__bf16)(v1.w*rs);
      bfv[j] = t;
    }
    #pragma unroll
    for (int i = 0; i < 8; i++) {
      int orow = wave*128 + i*16 + l16;
      bf16x8 afr = __builtin_bit_cast(bf16x8, *(const u16x8*)&woutt[(size_t)orow*512 + h*64 + ks*32 + quad*8]);
      #pragma unroll
      for (int j = 0; j < 4; j++)
        acc[i][j] = __builtin_amdgcn_mfma_f32_16x16x32_bf16(afr, bfv[j], acc[i][j], 0, 0, 0);
    }
  }
  u16* out = W2t + (size_t)b*262144;
  #pragma unroll
  for (int i = 0; i < 8; i++)
    #pragma unroll
    for (int j = 0; j < 4; j++)
      #pragma unroll
      for (int r = 0; r < 4; r++) {
        int orow = wave*128 + i*16 + quad*4 + r;
        out[(size_t)orow*512 + h*64 + j*16 + l16] = f2bf(acc[i][j][r]);
      }
}

// ---- batched attn GEMM (M-tile 64): attnb = bf16(qb[b] @ W2t[b]^T + b_out); fused masked cpad ----
// VALU-staged (v13): M-tile-64 has too little compute/chunk to cover a serial vmcnt drain.
__global__ __launch_bounds__(256) void mgemm_attn64_k(const u16* qb, const u16* W2t, const float* bias,
                                                      const int* mask, u16* attnb, u16* cpadb){
  __shared__ u16 As[64][40];
  __shared__ u16 Bs[128][40];
  int tid = threadIdx.x;
  int lane = tid & 63;
  int wave = tid >> 6;
  int wn = wave * 32;
  int quad = lane >> 4, l16 = lane & 15;
  int m0 = blockIdx.y * 64, n0 = blockIdx.x * 128, b = blockIdx.z;
  const u16* A  = qb  + (size_t)b*2048*512;
  const u16* Bt = W2t + (size_t)b*262144;
  fx4 acc[4][2] = {};
  int ar = tid >> 2;
  int ac = (tid & 3) * 8;
  for (int k0 = 0; k0 < 512; k0 += 32) {
    *(u16x8*)&As[ar][ac]    = *(const u16x8*)&A[(size_t)(m0+ar)*512 + k0 + ac];
    *(u16x8*)&Bs[ar][ac]    = *(const u16x8*)&Bt[(size_t)(n0+ar)*512 + k0 + ac];
    *(u16x8*)&Bs[ar+64][ac] = *(const u16x8*)&Bt[(size_t)(n0+ar+64)*512 + k0 + ac];
    __syncthreads();
    bf16x8 af[4], bfv[2];
    #pragma unroll
    for (int i = 0; i < 4; i++)
      af[i] = __builtin_bit_cast(bf16x8, *(const u16x8*)&As[i*16 + l16][quad*8]);
    #pragma unroll
    for (int j = 0; j < 2; j++)
      bfv[j] = __builtin_bit_cast(bf16x8, *(const u16x8*)&Bs[wn + j*16 + l16][quad*8]);
    #pragma unroll
    for (int i = 0; i < 4; i++)
      #pragma unroll
      for (int j = 0; j < 2; j++)
        acc[i][j] = __builtin_amdgcn_mfma_f32_16x16x32_bf16(af[i], bfv[j], acc[i][j], 0, 0, 0);
    __syncthreads();
  }
  #pragma unroll
  for (int i = 0; i < 4; i++)
    #pragma unroll
    for (int j = 0; j < 2; j++) {
      int col = n0 + wn + j*16 + l16;
      float bv = bias[col];
      #pragma unroll
      for (int r = 0; r < 4; r++) {
        int row_l = m0 + i*16 + quad*4 + r;
        float v = acc[i][j][r] + bv;
        u16 vbb = f2bf(v);
        attnb[((size_t)b*2048 + row_l)*512 + col] = vbb;
        int mk = mask[b*2048 + row_l];
        cpadb[((size_t)b*2088 + row_l + 20)*512 + col] = mk ? vbb : (u16)0;
      }
    }
}

// ---- conv v15 (measured ~74us on nominal machine; structure-bound) ----
#define A_ROWS 552
#define A_SZ (A_ROWS*32)    // u16 units
#define W_SZ (9*64*32)
__global__ __launch_bounds__(512, 2) void mconv15_k(const u16* cpad, const u16* Wn, const u16* Ww,
                                                    const float* bias_n, const float* bias_w,
                                                    u16* Dn, u16* Dw){
  __shared__ u16 As[2*A_SZ];      // rows of 64B, slot-swizzled content
  __shared__ u16 Ws[2*W_SZ];      // [kk][o] rows of 64B, slot-swizzled content
  int tid = threadIdx.x;
  int lane = tid & 63;
  int wave = tid >> 6;            // 0..7
  int wm = wave * 64;             // t-offset within 512
  int quad = lane >> 4, l16 = lane & 15;
  int o0 = blockIdx.x * 64, m0 = blockIdx.y * 512;
  int b = blockIdx.z >> 1, cid = blockIdx.z & 1;
  const u16* W = cid ? Ww : Wn;
  const float* bias = cid ? bias_w : bias_n;
  u16* D = cid ? Dw : Dn;
  fx4 acc[4][4] = {};
  const u16* cb = cpad + ((size_t)b*2088 + m0)*512;
  int wslot = ((quad ^ ((l16 >> 1) & 3)) * 8);
  int sbase = cid ? 0 : 16;
  int sstep = cid ? 5 : 1;
  int rowb0 = sbase + wm + l16;

  const u16* ap[5]; bool av[5];
  #pragma unroll
  for (int it = 0; it < 5; it++) {
    int s = it*512 + tid;
    av[it] = (s < 2208);
    int row = av[it] ? (s >> 2) : 0;
    int lsl = ((s & 3) ^ ((s >> 3) & 3)) * 8;
    ap[it] = cb + (size_t)row*512 + lsl;
  }
  const u16* wp[5]; bool wv[5];
  #pragma unroll
  for (int it = 0; it < 5; it++) {
    int s = it*512 + tid;
    wv[it] = (s < 2304);
    int kk = wv[it] ? (s >> 8) : 0;
    int ow = (s >> 2) & 63;
    int lsl = ((s & 3) ^ ((s >> 3) & 3)) * 8;
    wp[it] = W + (size_t)kk*262144 + (size_t)(o0 + ow)*512 + lsl;
  }

#define STAGE_CHUNK(c0, buf)                                                          \
  {                                                                                   \
    _Pragma("unroll")                                                                 \
    for (int it = 0; it < 5; it++) {                                                  \
      if (av[it])                                                                     \
        gload16(ap[it] + (c0), &As[(buf)*A_SZ + (it*512 + wave*64)*8]);               \
    }                                                                                 \
    _Pragma("unroll")                                                                 \
    for (int it = 0; it < 5; it++) {                                                  \
      if (wv[it])                                                                     \
        gload16(wp[it] + (c0), &Ws[(buf)*W_SZ + (it*512 + wave*64)*8]);               \
    }                                                                                 \
  }

#define LOADFRAG(kk, bfv, afr)                                                        \
  {                                                                                   \
    int rowb = rowb0 + sstep*(kk);                                                    \
    int aslot = ((quad ^ ((rowb >> 1) & 3)) * 8);                                     \
    _Pragma("unroll")                                                                 \
    for (int j = 0; j < 4; j++)                                                       \
      bfv[j] = __builtin_bit_cast(bf16x8,                                             \
                 *(const u16x8*)&Wsb[((kk)*64 + j*16 + l16)*32 + wslot]);             \
    _Pragma("unroll")                                                                 \
    for (int i = 0; i < 4; i++)                                                       \
      afr[i] = __builtin_bit_cast(bf16x8,                                             \
                 *(const u16x8*)&Asb[(rowb + i*16)*32 + aslot]);                      \
  }

#define MFMATAP_SGB(bfv, afr)                                                         \
  {                                                                                   \
    _Pragma("unroll")                                                                 \
    for (int i = 0; i < 4; i++)                                                       \
      _Pragma("unroll")                                                               \
      for (int j = 0; j < 4; j++)                                                     \
        acc[i][j] = __builtin_amdgcn_mfma_f32_16x16x32_bf16(afr[i], bfv[j],           \
                                                            acc[i][j], 0, 0, 0);      \
    _Pragma("unroll")                                                                 \
    for (int g = 0; g < 8; g++) {                                                     \
      __builtin_amdgcn_sched_group_barrier(0x008, 2, 0);  /* 2 MFMA */                \
      __builtin_amdgcn_sched_group_barrier(0x100, 1, 0);  /* 1 DS_READ */             \
    }                                                                                 \
  }

#define MFMATAP_PLAIN(bfv, afr)                                                       \
  {                                                                                   \
    _Pragma("unroll")                                                                 \
    for (int i = 0; i < 4; i++)                                                       \
      _Pragma("unroll")                                                               \
      for (int j = 0; j < 4; j++)                                                     \
        acc[i][j] = __builtin_amdgcn_mfma_f32_16x16x32_bf16(afr[i], bfv[j],           \
                                                            acc[i][j], 0, 0, 0);      \
  }

  STAGE_CHUNK(0, 0)
  __syncthreads();

  for (int ch = 0; ch < 16; ch++) {
    int cur = ch & 1;
    const u16* Asb = &As[cur*A_SZ];
    const u16* Wsb = &Ws[cur*W_SZ];
    bf16x8 bfvA[4], afrA[4], bfvB[4], afrB[4];
    LOADFRAG(0, bfvA, afrA)
    if (ch < 15) {
      int c0n = (ch + 1) * 32;
      int nb = cur ^ 1;
      STAGE_CHUNK(c0n, nb)
    }
    #pragma unroll
    for (int kt = 0; kt < 8; kt += 2) {
      LOADFRAG(kt+1, bfvB, afrB)
      MFMATAP_SGB(bfvA, afrA)
      LOADFRAG(kt+2, bfvA, afrA)
      MFMATAP_SGB(bfvB, afrB)
    }
    MFMATAP_PLAIN(bfvA, afrA)
    __syncthreads();
  }
#undef STAGE_CHUNK
#undef LOADFRAG
#undef MFMATAP_SGB
#undef MFMATAP_PLAIN
  #pragma unroll
  for (int i = 0; i < 4; i++)
    #pragma unroll
    for (int j = 0; j < 4; j++) {
      int col = o0 + j*16 + l16;
      float bv = bias[col];
      #pragma unroll
      for (int r = 0; r < 4; r++) {
        int row = b*2048 + m0 + wm + i*16 + quad*4 + r;
        D[(size_t)row*512 + col] = f2bf(geluf(acc[i][j][r] + bv));
      }
    }
}

// ---- ff GEMM v2: 128x128 tile, 512 threads, gload_lds staging + XOR swizzle ----
__global__ __launch_bounds__(512) void mgemm128b_k(const u16* A, const u16* Bt, const float* bias,
                                                   u16* C){
  __shared__ u16 As[128*32];
  __shared__ u16 Bs[128*32];
  int tid = threadIdx.x;
  int lane = tid & 63;
  int wave = tid >> 6;          // 0..7
  int wm = (wave >> 2) * 64;    // 0 or 64
  int wn = (wave & 3) * 32;     // 0,32,64,96
  int quad = lane >> 4, l16 = lane & 15;
  int m0 = blockIdx.y * 128, n0 = blockIdx.x * 128;
  fx4 acc[4][2] = {};
  for (int k0 = 0; k0 < 512; k0 += 32) {
    {
      int s = tid;
      int lsl = ((s & 3) ^ ((s >> 3) & 3)) * 8;
      gload16(&A[(size_t)(m0 + (s >> 2))*512 + k0 + lsl], &As[(wave*64)*8]);
    }
    {
      int s = tid;
      int lsl = ((s & 3) ^ ((s >> 3) & 3)) * 8;
      gload16(&Bt[(size_t)(n0 + (s >> 2))*512 + k0 + lsl], &Bs[(wave*64)*8]);
    }
    __syncthreads();
    bf16x8 af[4], bfv[2];
    #pragma unroll
    for (int i = 0; i < 4; i++) {
      int row = wm + i*16 + l16;
      af[i] = __builtin_bit_cast(bf16x8,
                *(const u16x8*)&As[row*32 + ((quad ^ ((row >> 1) & 3)) * 8)]);
    }
    #pragma unroll
    for (int j = 0; j < 2; j++) {
      int row = wn + j*16 + l16;
      bfv[j] = __builtin_bit_cast(bf16x8,
                *(const u16x8*)&Bs[row*32 + ((quad ^ ((row >> 1) & 3)) * 8)]);
    }
    #pragma unroll
    for (int i = 0; i < 4; i++)
      #pragma unroll
      for (int j = 0; j < 2; j++)
        acc[i][j] = __builtin_amdgcn_mfma_f32_16x16x32_bf16(af[i], bfv[j], acc[i][j], 0, 0, 0);
    __syncthreads();
  }
  #pragma unroll
  for (int i = 0; i < 4; i++)
    #pragma unroll
    for (int j = 0; j < 2; j++) {
      int col = n0 + wn + j*16 + l16;
      float bv = bias[col];
      #pragma unroll
      for (int r = 0; r < 4; r++) {
        int row = m0 + wm + i*16 + quad*4 + r;
        C[(size_t)row*512 + col] = f2bf(geluf(acc[i][j][r] + bv));
      }
    }
}

// LN wave-per-row: 4 rows/block (one per wave), u16x8 loads (8 elems/lane), pure
// shfl_xor reduction — no barriers, no LDS. NADD extra inputs; OM as before.
template<int NADD, int OM>
__global__ __launch_bounds__(256) void lnw_k(const u16* X, const u16* Y, const u16* Z,
                                             const float* g, const float* be,
                                             const int* flags, void* out){
  int wave = threadIdx.x >> 6, lane = threadIdx.x & 63;
  size_t row = (size_t)blockIdx.x*4 + wave;
  int c = lane*8;
  float x[8];
  {
    u16x8 xv = *(const u16x8*)&X[row*512 + c];
    #pragma unroll
    for (int t = 0; t < 8; t++) x[t] = bf2f(xv[t]);
  }
  if (NADD >= 1) {
    u16x8 yv = *(const u16x8*)&Y[row*512 + c];
    #pragma unroll
    for (int t = 0; t < 8; t++) x[t] += bf2f(yv[t]);
  }
  if (NADD >= 2) {
    u16x8 zv = *(const u16x8*)&Z[row*512 + c];
    #pragma unroll
    for (int t = 0; t < 8; t++) x[t] += bf2f(zv[t]);
  }
  float s = 0.0f;
  #pragma unroll
  for (int t = 0; t < 8; t++) s += x[t];
  #pragma unroll
  for (int o = 32; o; o >>= 1) s += __shfl_xor(s, o, 64);
  float mean = s * (1.0f/512.0f);
  float d[8], s2 = 0.0f;
  #pragma unroll
  for (int t = 0; t < 8; t++) { d[t] = x[t] - mean; s2 += d[t]*d[t]; }
  #pragma unroll
  for (int o = 32; o; o >>= 1) s2 += __shfl_xor(s2, o, 64);
  float inv = rsqrtf(s2 * (1.0f/512.0f) + 1e-5f);
  float4 g0 = *(const float4*)&g[c],  g1 = *(const float4*)&g[c+4];
  float4 b0 = *(const float4*)&be[c], b1 = *(const float4*)&be[c+4];
  float r[8];
  r[0] = d[0]*inv*g0.x + b0.x; r[1] = d[1]*inv*g0.y + b0.y;
  r[2] = d[2]*inv*g0.z + b0.z; r[3] = d[3]*inv*g0.w + b0.w;
  r[4] = d[4]*inv*g1.x + b1.x; r[5] = d[5]*inv*g1.y + b1.y;
  r[6] = d[6]*inv*g1.z + b1.z; r[7] = d[7]*inv*g1.w + b1.w;
  bool obf = (OM == 1) || (OM == 2 && !flags[0]);
  if (obf) {
    u16x8 ov;
    #pragma unroll
    for (int t = 0; t < 8; t++) ov[t] = f2bf(r[t]);
    *(u16x8*)&((u16*)out)[row*512 + c] = ov;
  } else {
    float* op = (float*)out + row*512 + c;
    *(float4*)op       = (float4){r[0], r[1], r[2], r[3]};
    *(float4*)(op + 4) = (float4){r[4], r[5], r[6], r[7]};
  }
}

extern "C" void kernel_launch(void* const* d_in, const int* in_sizes, int n_in,
                              void* d_out, int out_size, void* d_ws, size_t ws_size,
                              hipStream_t stream) {
  const void* tokens   = d_in[0];
  const void* mask     = d_in[1];
  const void* w_qkv    = d_in[2];
  const void* w_out    = d_in[3];
  const void* b_out    = d_in[4];
  const void* w_narrow = d_in[5];
  const void* b_narrow = d_in[6];
  const void* w_wide   = d_in[7];
  const void* b_wide   = d_in[8];
  const void* ln1_g    = d_in[9];
  const void* ln1_b    = d_in[10];
  const void* ff_w     = d_in[11];
  const void* ff_b     = d_in[12];
  const void* ln2_g    = d_in[13];
  const void* ln2_b    = d_in[14];

  float* ws = (float*)d_ws;
  int*   flags  = (int*)ws;                    // 16
  int*   m32    = (int*)(ws + 16);             // 8192 -> 8208
  float* params = ws + 8208;                   // 4096 -> 12304
  float* kS     = ws + 12304;                  // 2048 -> 14352
  float* ctx    = ws + 14352;                  // 131072 -> 145424
  float* rope   = ws + 145424;                 // 131072 -> 276496
  u16*   tokbf  = (u16*)(ws + 276496);         // 4194304 u16 -> 2373648
  u16*   wqkvt  = (u16*)(ws + 2373648);        // 786432 u16 -> 2766864
  u16*   woutt  = (u16*)(ws + 2766864);        // 262144 u16 -> 2897936
  u16*   ffwt   = (u16*)(ws + 2897936);        // 262144 u16 -> 3029008
  u16*   wtN2   = (u16*)(ws + 3029008);        // 2359296 u16 -> 4208656
  u16*   wtW2   = (u16*)(ws + 4208656);        // 2359296 u16 -> 5388304
  u16*   qb     = (u16*)(ws + 5388304);        // 4194304 u16 -> 7485456
  u16*   keb    = (u16*)(ws + 7485456);        // 4194304 u16 -> 9582608
  u16*   vb     = (u16*)(ws + 9582608);        // 4194304 u16 -> 11679760
  u16*   W2t    = (u16*)(ws + 11679760);       // 1048576 u16 -> 12204048
  u16*   attnb  = (u16*)(ws + 12204048);       // 4194304 u16 -> 14301200
  u16*   cpadb  = (u16*)(ws + 14301200);       // 4276224 u16 -> 16439312
  u16*   Dnb    = (u16*)(ws + 16439312);       // 4194304 u16 -> 18536464
  u16*   Dwb    = (u16*)(ws + 18536464);       // 4194304 u16 -> 20633616 (~82.5 MB)
  u16*   Eb     = attnb;                       // attnb dead after ln1
  u16*   t1b    = tokbf;                       // tokbf dead after qkv gemm

  float* p_bout = params;        float* p_bnar = params + 512;
  float* p_bwid = params + 1024; float* p_l1g  = params + 1536;
  float* p_l1b  = params + 2048; float* p_ffb  = params + 2560;
  float* p_l2g  = params + 3072; float* p_l2b  = params + 3584;

  sniff_k<<<dim3(1), dim3(256), 0, stream>>>((const u16*)tokens, (const unsigned int*)mask, flags);

  // merged preprocessing: misc (4096) + conv weight prep (1024) + transpose (576)
  misc2_k<<<dim3(5696), dim3(256), 0, stream>>>(mask, tokens, b_out, b_narrow, b_wide, ln1_g, ln1_b,
                                                ff_b, ln2_g, ln2_b, flags, rope, m32, params, ctx,
                                                kS, tokbf, w_qkv, w_out, ff_w, w_narrow, w_wide,
                                                wqkvt, woutt, ffwt, wtN2, wtW2);

  // qkv GEMM; A = tokens directly when input already bf16 (tokbf only on f32 path)
  mgemm_qkv_k<<<dim3(12, 64), dim3(256), 0, stream>>>(
      tokens, tokbf, wqkvt, rope, m32, flags, qb, keb, vb);

  // ctx = ke^T @ v (+ S accumulation), atomic version (R10)
  ctx_k<<<dim3(32, 8), dim3(256), 0, stream>>>(keb, vb, ctx, kS);

  // W2t[b] = (blockdiag(ctx_b)/S) @ w_out; + cpad edge zero
  ctxw_k<<<dim3(352), dim3(256), 0, stream>>>(ctx, kS, woutt, W2t, cpadb);

  // attn = qb @ W2t[b]^T + b_out (bf16); fused masked cpad write
  mgemm_attn64_k<<<dim3(4, 32, 4), dim3(256), 0, stream>>>(qb, W2t, p_bout, m32, attnb, cpadb);

  // convs: v13 schedule + hoisted staging addresses
  mconv15_k<<<dim3(8, 4, 8), dim3(512), 0, stream>>>(cpadb, wtN2, wtW2, p_bnar, p_bwid, Dnb, Dwb);

  // t1 = LN(attn + Dn + Dw) -> bf16 (wave-per-row)
  lnw_k<2,1><<<dim3(NROWS/4), dim3(256), 0, stream>>>(attnb, Dnb, Dwb, p_l1g, p_l1b, flags, (void*)t1b);

  // E = gelu(t1 @ ff_w + ff_b) -> bf16
  mgemm128b_k<<<dim3(4, 64), dim3(512), 0, stream>>>(t1b, ffwt, p_ffb, Eb);

  // out = LN(E) -> d_out, dtype per flags (wave-per-row)
  lnw_k<0,2><<<dim3(NROWS/4), dim3(256), 0, stream>>>(Eb, nullptr, nullptr, p_l2g, p_l2b, flags, d_out);
}